// Round 5
// baseline (250.924 us; speedup 1.0000x reference)
//
#include <hip/hip_runtime.h>
#include <hip/hip_bf16.h>

#define Nn 2
#define Ss 16
#define Cc 64
#define Hh 128
#define Ww 160
#define Gg 8

// ---------------------------------------------------------------------------
// Transpose [N,C,H,W] -> [N,H,W,C] via LDS tile (C=64 x WT=32), conflict-free.
// ---------------------------------------------------------------------------
__global__ __launch_bounds__(256) void transpose_nchw_nhwc(
    const float* __restrict__ src, float* __restrict__ dst) {
  const int WT = 32;
  __shared__ float tile[Cc][WT + 1];  // +1 pad: write-phase reads stride 33 -> 2-way max (free)
  int b = blockIdx.x;
  int wt = b % (Ww / WT);
  int h  = (b / (Ww / WT)) % Hh;
  int n  = b / ((Ww / WT) * Hh);
  int w0 = wt * WT;
  int tid = threadIdx.x;
#pragma unroll
  for (int i = 0; i < (Cc * WT) / 256; ++i) {  // 8 iters
    int idx = tid + i * 256;
    int c  = idx >> 5;   // /32
    int ww = idx & 31;
    tile[c][ww] = src[((n * Cc + c) * Hh + h) * Ww + w0 + ww];
  }
  __syncthreads();
#pragma unroll
  for (int i = 0; i < (Cc * WT) / 256; ++i) {
    int idx = tid + i * 256;
    int ww = idx >> 6;   // /64
    int c  = idx & 63;
    dst[((n * Hh + h) * Ww + w0 + ww) * Cc + c] = tile[c][ww];
  }
}

// ---------------------------------------------------------------------------
// Main kernel: one wave per (n,h,w) point, lane = channel, loop over all s.
// NHWC=true : ref/src are [N,H,W,C] (from workspace transpose) -> coalesced
// NHWC=false: ref/src are [N,C,H,W] (fallback, uncoalesced but correct)
// ---------------------------------------------------------------------------
template <bool NHWC>
__global__ __launch_bounds__(256) void corr_kernel(
    const float* __restrict__ ref, const float* __restrict__ src,
    const float* __restrict__ grids, const float* __restrict__ mask,
    float* __restrict__ corr, float* __restrict__ wmask) {
  const int HW = Hh * Ww;
  int gw   = blockIdx.x * 4 + (threadIdx.x >> 6);  // global wave id = point id
  int lane = threadIdx.x & 63;
  int w  = gw % Ww;
  int hn = gw / Ww;
  int h  = hn % Hh;
  int n  = hn / Hh;

  // feat_ref channel vector for this point: loaded ONCE, reused for all 16 s.
  float rv = NHWC ? ref[((n * Hh + h) * Ww + w) * Cc + lane]
                  : ref[((n * Cc + lane) * Hh + h) * Ww + w];

#pragma unroll 4
  for (int s = 0; s < Ss; ++s) {
    int gbase = (((n * Ss + s) * 2) * Hh + h) * Ww + w;
    float xg = grids[gbase];
    float yg = grids[gbase + HW];
    float mk = mask[((n * Ss + s) * Hh + h) * Ww + w];

    // Mirror reference arithmetic exactly (f32): normalize then denormalize.
    float xn = 2.0f * xg / (float)Ww - 1.0f;
    float yn = 2.0f * yg / (float)Hh - 1.0f;
    float gx = ((xn + 1.0f) * (float)Ww - 1.0f) * 0.5f;
    float gy = ((yn + 1.0f) * (float)Hh - 1.0f) * 0.5f;

    float x0f = floorf(gx), y0f = floorf(gy);
    float dx = gx - x0f, dy = gy - y0f;
    int x0 = (int)x0f, y0 = (int)y0f;
    int x1 = x0 + 1, y1 = y0 + 1;

    float vx0 = (x0 >= 0 && x0 < Ww) ? 1.f : 0.f;
    float vx1 = (x1 >= 0 && x1 < Ww) ? 1.f : 0.f;
    float vy0 = (y0 >= 0 && y0 < Hh) ? 1.f : 0.f;
    float vy1 = (y1 >= 0 && y1 < Hh) ? 1.f : 0.f;

    float w00 = (1.f - dx) * (1.f - dy) * vx0 * vy0;
    float w10 = dx * (1.f - dy) * vx1 * vy0;
    float w01 = (1.f - dx) * dy * vx0 * vy1;
    float w11 = dx * dy * vx1 * vy1;

    float m  = w00 + w10 + w01 + w11;          // == grid_sample of ones
    float wm = (m < 0.9999f) ? 0.f : 1.f;      // warping mask
    float scale = wm * mk;

    float res = 0.f;
    if (scale != 0.f) {  // wave-uniform branch (all operands lane-uniform)
      int x0c = min(max(x0, 0), Ww - 1), x1c = min(max(x1, 0), Ww - 1);
      int y0c = min(max(y0, 0), Hh - 1), y1c = min(max(y1, 0), Hh - 1);
      float v00, v10, v01, v11;
      if (NHWC) {
        v00 = src[((n * Hh + y0c) * Ww + x0c) * Cc + lane];
        v10 = src[((n * Hh + y0c) * Ww + x1c) * Cc + lane];
        v01 = src[((n * Hh + y1c) * Ww + x0c) * Cc + lane];
        v11 = src[((n * Hh + y1c) * Ww + x1c) * Cc + lane];
      } else {
        const float* sp = src + (size_t)(n * Cc + lane) * HW;
        v00 = sp[y0c * Ww + x0c];
        v10 = sp[y0c * Ww + x1c];
        v01 = sp[y1c * Ww + x0c];
        v11 = sp[y1c * Ww + x1c];
      }
      float acc = w00 * v00 + w10 * v10 + w01 * v01 + w11 * v11;
      float p = acc * rv * scale;
      // sum over the 8 channels of this lane's group (lanes g*8 .. g*8+7)
      p += __shfl_xor(p, 1);
      p += __shfl_xor(p, 2);
      p += __shfl_xor(p, 4);
      res = p;
    }
    if ((lane & 7) == 0) {
      int g = lane >> 3;
      // write-once data: nontemporal keeps L2 for the gather working set
      __builtin_nontemporal_store(res, &corr[((((n * Gg + g) * Ss + s) * Hh + h) * Ww) + w]);
    }
    if (lane == 0)
      __builtin_nontemporal_store(scale, &wmask[((n * Ss + s) * Hh + h) * Ww + w]);
  }
}

extern "C" void kernel_launch(void* const* d_in, const int* in_sizes, int n_in,
                              void* d_out, int out_size, void* d_ws, size_t ws_size,
                              hipStream_t stream) {
  const float* feat_ref = (const float*)d_in[0];
  const float* feat_src = (const float*)d_in[1];
  const float* grids    = (const float*)d_in[2];
  const float* mask     = (const float*)d_in[3];

  float* corr  = (float*)d_out;
  float* wmask = corr + (size_t)Nn * Gg * Ss * Hh * Ww;

  const size_t per = (size_t)Nn * Cc * Hh * Ww;  // 2,621,440 floats = 10.5 MB
  const int n_waves  = Nn * Hh * Ww;             // 40,960 waves (one per point)
  const int n_blocks = n_waves / 4;              // 256-thread blocks = 4 waves

  if (ws_size >= 2 * per * sizeof(float)) {
    float* ref_t = (float*)d_ws;
    float* src_t = ref_t + per;
    const int t_blocks = Nn * Hh * (Ww / 32);    // 1280
    transpose_nchw_nhwc<<<t_blocks, 256, 0, stream>>>(feat_ref, ref_t);
    transpose_nchw_nhwc<<<t_blocks, 256, 0, stream>>>(feat_src, src_t);
    corr_kernel<true><<<n_blocks, 256, 0, stream>>>(ref_t, src_t, grids, mask, corr, wmask);
  } else {
    corr_kernel<false><<<n_blocks, 256, 0, stream>>>(feat_ref, feat_src, grids, mask, corr, wmask);
  }
}

// Round 8
// 170.153 us; speedup vs baseline: 1.4747x; 1.4747x over previous
//
#include <hip/hip_runtime.h>
#include <hip/hip_bf16.h>

#define Nn 2
#define Ss 16
#define Cc 64
#define Hh 128
#define Ww 160
#define Gg 8
#define HW (Hh * Ww)        // 20480
#define NPS (Nn * Ss * HW)  // 655360

struct Prep {
  float4 w;  // bilinear weights, pre-multiplied by (warping_mask * mask)
  int4 o;    // clamped gather offsets (y*W+x) for corners 00,10,01,11
};

// ---------------------------------------------------------------------------
// Transpose [N,C,H,W] -> [N,H,W,C]; blockIdx.y selects {ref, src}.
// ---------------------------------------------------------------------------
__global__ __launch_bounds__(256) void transpose2_nchw_nhwc(
    const float* __restrict__ ref, const float* __restrict__ srcf,
    float* __restrict__ ref_t, float* __restrict__ src_t) {
  const float* sp = blockIdx.y ? srcf : ref;
  float* dp = blockIdx.y ? src_t : ref_t;
  const int WT = 32;
  __shared__ float tile[Cc][WT + 1];
  int b = blockIdx.x;                 // N*H*(W/32) = 1280
  int wt = b % (Ww / WT);
  int h  = (b / (Ww / WT)) % Hh;
  int n  = b / ((Ww / WT) * Hh);
  int w0 = wt * WT;
  int tid = threadIdx.x;
#pragma unroll
  for (int i = 0; i < (Cc * WT) / 256; ++i) {
    int idx = tid + i * 256;
    int c  = idx >> 5;
    int ww = idx & 31;
    tile[c][ww] = sp[((n * Cc + c) * Hh + h) * Ww + w0 + ww];
  }
  __syncthreads();
#pragma unroll
  for (int i = 0; i < (Cc * WT) / 256; ++i) {
    int idx = tid + i * 256;
    int ww = idx >> 6;
    int c  = idx & 63;
    dp[((n * Hh + h) * Ww + w0 + ww) * Cc + c] = tile[c][ww];
  }
}

// ---------------------------------------------------------------------------
// Prep: thread per (n,s,h,w). All lanes do DIFFERENT points -> no redundant
// uniform math (this was 75% VALUBusy in the wave-per-point version).
// grid = dim3(HW/256, N*S)
// ---------------------------------------------------------------------------
__global__ __launch_bounds__(256) void prep_kernel(
    const float* __restrict__ grids, const float* __restrict__ mask,
    Prep* __restrict__ prep, float* __restrict__ wmask) {
  int hw = blockIdx.x * 256 + threadIdx.x;
  int ns = blockIdx.y;                 // n*S + s
  int idx = ns * HW + hw;

  float xg = grids[(ns * 2) * HW + hw];
  float yg = grids[(ns * 2 + 1) * HW + hw];
  float mk = mask[idx];

  // Mirror reference arithmetic exactly (f32).
  float xn = 2.0f * xg / (float)Ww - 1.0f;
  float yn = 2.0f * yg / (float)Hh - 1.0f;
  float gx = ((xn + 1.0f) * (float)Ww - 1.0f) * 0.5f;
  float gy = ((yn + 1.0f) * (float)Hh - 1.0f) * 0.5f;

  float x0f = floorf(gx), y0f = floorf(gy);
  float dx = gx - x0f, dy = gy - y0f;
  int x0 = (int)x0f, y0 = (int)y0f;
  int x1 = x0 + 1, y1 = y0 + 1;

  float vx0 = (x0 >= 0 && x0 < Ww) ? 1.f : 0.f;
  float vx1 = (x1 >= 0 && x1 < Ww) ? 1.f : 0.f;
  float vy0 = (y0 >= 0 && y0 < Hh) ? 1.f : 0.f;
  float vy1 = (y1 >= 0 && y1 < Hh) ? 1.f : 0.f;

  float w00 = (1.f - dx) * (1.f - dy) * vx0 * vy0;
  float w10 = dx * (1.f - dy) * vx1 * vy0;
  float w01 = (1.f - dx) * dy * vx0 * vy1;
  float w11 = dx * dy * vx1 * vy1;

  float m  = w00 + w10 + w01 + w11;
  float wm = (m < 0.9999f) ? 0.f : 1.f;
  float scale = wm * mk;

  int x0c = min(max(x0, 0), Ww - 1), x1c = min(max(x1, 0), Ww - 1);
  int y0c = min(max(y0, 0), Hh - 1), y1c = min(max(y1, 0), Hh - 1);

  Prep p;
  p.w = make_float4(w00 * scale, w10 * scale, w01 * scale, w11 * scale);
  p.o = make_int4(y0c * Ww + x0c, y0c * Ww + x1c, y1c * Ww + x0c, y1c * Ww + x1c);
  prep[idx] = p;
  wmask[idx] = scale;   // plain store: lets L2 coalesce full lines
}

// ---------------------------------------------------------------------------
// Main: wave per point, lane = channel, loop s. All heavy uniform math gone.
// grid = dim3(HW/4, N). XCD-chunked swizzle keeps consecutive hw on one XCD
// so corr stores coalesce to full lines inside a single L2.
// ---------------------------------------------------------------------------
__global__ __launch_bounds__(256) void corr_main(
    const float* __restrict__ ref_t, const float* __restrict__ src_t,
    const Prep* __restrict__ prep, float* __restrict__ corr) {
  int nwg = gridDim.x;                     // 5120, divisible by 8
  int q = nwg >> 3;
  int b = blockIdx.x;
  int swz = (b & 7) * q + (b >> 3);        // bijective XCD chunking
  int wid  = threadIdx.x >> 6;
  int lane = threadIdx.x & 63;
  int hw = swz * 4 + wid;
  int n  = blockIdx.y;

  float rv = ref_t[(n * HW + hw) * Cc + lane];
  const float* srcn = src_t + (size_t)n * HW * Cc;
  const Prep* pp = prep + (size_t)(n * Ss) * HW + hw;
  // per-lane corr base: ((n*G + g)*S)*HW + hw, g = lane>>3
  int cbase = ((n * Gg + (lane >> 3)) * Ss) * HW + hw;

  float4 w = pp->w;
  int4   o = pp->o;
#pragma unroll
  for (int s = 0; s < Ss; ++s) {
    float4 wN; int4 oN;
    if (s + 1 < Ss) {                      // prefetch next-s uniforms
      wN = pp[(s + 1) * HW].w;
      oN = pp[(s + 1) * HW].o;
    }
    float v00 = srcn[o.x * Cc + lane];
    float v10 = srcn[o.y * Cc + lane];
    float v01 = srcn[o.z * Cc + lane];
    float v11 = srcn[o.w * Cc + lane];
    float acc = w.x * v00;
    acc = fmaf(w.y, v10, acc);
    acc = fmaf(w.z, v01, acc);
    acc = fmaf(w.w, v11, acc);
    float p = acc * rv;
    p += __shfl_xor(p, 1);
    p += __shfl_xor(p, 2);
    p += __shfl_xor(p, 4);
    if ((lane & 7) == 0) corr[cbase + s * HW] = p;
    w = wN; o = oN;
  }
}

// ---------------------------------------------------------------------------
// Legacy single-kernel path (fallback when ws can't hold prep buffer).
// Identical to R5 but with plain (cached) stores — NT caused 5.8x write amp.
// ---------------------------------------------------------------------------
template <bool NHWC>
__global__ __launch_bounds__(256) void corr_kernel(
    const float* __restrict__ ref, const float* __restrict__ src,
    const float* __restrict__ grids, const float* __restrict__ mask,
    float* __restrict__ corr, float* __restrict__ wmask) {
  int gw   = blockIdx.x * 4 + (threadIdx.x >> 6);
  int lane = threadIdx.x & 63;
  int w  = gw % Ww;
  int hn = gw / Ww;
  int h  = hn % Hh;
  int n  = hn / Hh;

  float rv = NHWC ? ref[((n * Hh + h) * Ww + w) * Cc + lane]
                  : ref[((n * Cc + lane) * Hh + h) * Ww + w];

#pragma unroll 4
  for (int s = 0; s < Ss; ++s) {
    int gbase = (((n * Ss + s) * 2) * Hh + h) * Ww + w;
    float xg = grids[gbase];
    float yg = grids[gbase + HW];
    float mk = mask[((n * Ss + s) * Hh + h) * Ww + w];

    float xn = 2.0f * xg / (float)Ww - 1.0f;
    float yn = 2.0f * yg / (float)Hh - 1.0f;
    float gx = ((xn + 1.0f) * (float)Ww - 1.0f) * 0.5f;
    float gy = ((yn + 1.0f) * (float)Hh - 1.0f) * 0.5f;

    float x0f = floorf(gx), y0f = floorf(gy);
    float dx = gx - x0f, dy = gy - y0f;
    int x0 = (int)x0f, y0 = (int)y0f;
    int x1 = x0 + 1, y1 = y0 + 1;

    float vx0 = (x0 >= 0 && x0 < Ww) ? 1.f : 0.f;
    float vx1 = (x1 >= 0 && x1 < Ww) ? 1.f : 0.f;
    float vy0 = (y0 >= 0 && y0 < Hh) ? 1.f : 0.f;
    float vy1 = (y1 >= 0 && y1 < Hh) ? 1.f : 0.f;

    float w00 = (1.f - dx) * (1.f - dy) * vx0 * vy0;
    float w10 = dx * (1.f - dy) * vx1 * vy0;
    float w01 = (1.f - dx) * dy * vx0 * vy1;
    float w11 = dx * dy * vx1 * vy1;

    float m  = w00 + w10 + w01 + w11;
    float wm = (m < 0.9999f) ? 0.f : 1.f;
    float scale = wm * mk;

    float res = 0.f;
    if (scale != 0.f) {
      int x0c = min(max(x0, 0), Ww - 1), x1c = min(max(x1, 0), Ww - 1);
      int y0c = min(max(y0, 0), Hh - 1), y1c = min(max(y1, 0), Hh - 1);
      float v00, v10, v01, v11;
      if (NHWC) {
        v00 = src[((n * Hh + y0c) * Ww + x0c) * Cc + lane];
        v10 = src[((n * Hh + y0c) * Ww + x1c) * Cc + lane];
        v01 = src[((n * Hh + y1c) * Ww + x0c) * Cc + lane];
        v11 = src[((n * Hh + y1c) * Ww + x1c) * Cc + lane];
      } else {
        const float* sp2 = src + (size_t)(n * Cc + lane) * HW;
        v00 = sp2[y0c * Ww + x0c];
        v10 = sp2[y0c * Ww + x1c];
        v01 = sp2[y1c * Ww + x0c];
        v11 = sp2[y1c * Ww + x1c];
      }
      float acc = w00 * v00 + w10 * v10 + w01 * v01 + w11 * v11;
      float p = acc * rv * scale;
      p += __shfl_xor(p, 1);
      p += __shfl_xor(p, 2);
      p += __shfl_xor(p, 4);
      res = p;
    }
    if ((lane & 7) == 0) {
      int g = lane >> 3;
      corr[((((n * Gg + g) * Ss + s) * Hh + h) * Ww) + w] = res;
    }
    if (lane == 0) wmask[((n * Ss + s) * Hh + h) * Ww + w] = scale;
  }
}

extern "C" void kernel_launch(void* const* d_in, const int* in_sizes, int n_in,
                              void* d_out, int out_size, void* d_ws, size_t ws_size,
                              hipStream_t stream) {
  const float* feat_ref = (const float*)d_in[0];
  const float* feat_src = (const float*)d_in[1];
  const float* grids    = (const float*)d_in[2];
  const float* mask     = (const float*)d_in[3];

  float* corr  = (float*)d_out;
  float* wmask = corr + (size_t)Nn * Gg * Ss * HW;

  const size_t bytes_t   = (size_t)Nn * Cc * HW * sizeof(float);  // 10.49 MB
  const size_t prep_off  = 2 * bytes_t;                           // 20.97 MB
  const size_t prep_size = (size_t)NPS * sizeof(Prep);            // 20.97 MB

  if (ws_size >= prep_off + prep_size) {            // 40 MiB full path
    float* ref_t = (float*)d_ws;
    float* src_t = ref_t + (size_t)Nn * Cc * HW;
    Prep*  prep  = (Prep*)((char*)d_ws + prep_off);
    prep_kernel<<<dim3(HW / 256, Nn * Ss), 256, 0, stream>>>(grids, mask, prep, wmask);
    transpose2_nchw_nhwc<<<dim3(Nn * Hh * (Ww / 32), 2), 256, 0, stream>>>(
        feat_ref, feat_src, ref_t, src_t);
    corr_main<<<dim3(HW / 4, Nn), 256, 0, stream>>>(ref_t, src_t, prep, corr);
  } else if (ws_size >= 2 * bytes_t) {              // transpose-only path
    float* ref_t = (float*)d_ws;
    float* src_t = ref_t + (size_t)Nn * Cc * HW;
    transpose2_nchw_nhwc<<<dim3(Nn * Hh * (Ww / 32), 2), 256, 0, stream>>>(
        feat_ref, feat_src, ref_t, src_t);
    corr_kernel<true><<<(Nn * HW) / 4, 256, 0, stream>>>(ref_t, src_t, grids, mask, corr, wmask);
  } else {                                          // no-workspace fallback
    corr_kernel<false><<<(Nn * HW) / 4, 256, 0, stream>>>(feat_ref, feat_src, grids, mask, corr, wmask);
  }
}

// Round 9
// 153.965 us; speedup vs baseline: 1.6297x; 1.1051x over previous
//
#include <hip/hip_runtime.h>
#include <hip/hip_bf16.h>

#define Nn 2
#define Ss 16
#define Cc 64
#define Hh 128
#define Ww 160
#define Gg 8
#define HW (Hh * Ww)        // 20480
#define NPS (Nn * Ss * HW)  // 655360

struct WO { float w; int o; };  // one corner: folded weight + clamped pixel offset

// ---------------------------------------------------------------------------
// Transpose [N,C,H,W] -> [N,H,W,C]; blockIdx.y selects {ref, src}.
// ---------------------------------------------------------------------------
__global__ __launch_bounds__(256) void transpose2_nchw_nhwc(
    const float* __restrict__ ref, const float* __restrict__ srcf,
    float* __restrict__ ref_t, float* __restrict__ src_t) {
  const float* sp = blockIdx.y ? srcf : ref;
  float* dp = blockIdx.y ? src_t : ref_t;
  const int WT = 32;
  __shared__ float tile[Cc][WT + 1];
  int b = blockIdx.x;                 // N*H*(W/32) = 1280
  int wt = b % (Ww / WT);
  int h  = (b / (Ww / WT)) % Hh;
  int n  = b / ((Ww / WT) * Hh);
  int w0 = wt * WT;
  int tid = threadIdx.x;
#pragma unroll
  for (int i = 0; i < (Cc * WT) / 256; ++i) {
    int idx = tid + i * 256;
    int c  = idx >> 5;
    int ww = idx & 31;
    tile[c][ww] = sp[((n * Cc + c) * Hh + h) * Ww + w0 + ww];
  }
  __syncthreads();
#pragma unroll
  for (int i = 0; i < (Cc * WT) / 256; ++i) {
    int idx = tid + i * 256;
    int ww = idx >> 6;
    int c  = idx & 63;
    dp[((n * Hh + h) * Ww + w0 + ww) * Cc + c] = tile[c][ww];
  }
}

// ---------------------------------------------------------------------------
// Prep: thread per (n,s,h,w); writes interleaved {w,o}[4] per point so each
// quarter-wave of corr_main loads its own corner in one 8 B access.
// grid = dim3(HW/256, N*S)
// ---------------------------------------------------------------------------
__global__ __launch_bounds__(256) void prep_kernel(
    const float* __restrict__ grids, const float* __restrict__ mask,
    WO* __restrict__ prep, float* __restrict__ wmask) {
  int hw = blockIdx.x * 256 + threadIdx.x;
  int ns = blockIdx.y;                 // n*S + s
  int idx = ns * HW + hw;

  float xg = grids[(ns * 2) * HW + hw];
  float yg = grids[(ns * 2 + 1) * HW + hw];
  float mk = mask[idx];

  // Mirror reference arithmetic exactly (f32).
  float xn = 2.0f * xg / (float)Ww - 1.0f;
  float yn = 2.0f * yg / (float)Hh - 1.0f;
  float gx = ((xn + 1.0f) * (float)Ww - 1.0f) * 0.5f;
  float gy = ((yn + 1.0f) * (float)Hh - 1.0f) * 0.5f;

  float x0f = floorf(gx), y0f = floorf(gy);
  float dx = gx - x0f, dy = gy - y0f;
  int x0 = (int)x0f, y0 = (int)y0f;
  int x1 = x0 + 1, y1 = y0 + 1;

  float vx0 = (x0 >= 0 && x0 < Ww) ? 1.f : 0.f;
  float vx1 = (x1 >= 0 && x1 < Ww) ? 1.f : 0.f;
  float vy0 = (y0 >= 0 && y0 < Hh) ? 1.f : 0.f;
  float vy1 = (y1 >= 0 && y1 < Hh) ? 1.f : 0.f;

  float w00 = (1.f - dx) * (1.f - dy) * vx0 * vy0;
  float w10 = dx * (1.f - dy) * vx1 * vy0;
  float w01 = (1.f - dx) * dy * vx0 * vy1;
  float w11 = dx * dy * vx1 * vy1;

  float m  = w00 + w10 + w01 + w11;
  float wm = (m < 0.9999f) ? 0.f : 1.f;
  float scale = wm * mk;

  int x0c = min(max(x0, 0), Ww - 1), x1c = min(max(x1, 0), Ww - 1);
  int y0c = min(max(y0, 0), Hh - 1), y1c = min(max(y1, 0), Hh - 1);

  // Interleaved {w,o} pairs, two 16 B stores (32 B contiguous per thread).
  int4 a, b;
  a.x = __float_as_int(w00 * scale); a.y = y0c * Ww + x0c;
  a.z = __float_as_int(w10 * scale); a.w = y0c * Ww + x1c;
  b.x = __float_as_int(w01 * scale); b.y = y1c * Ww + x0c;
  b.z = __float_as_int(w11 * scale); b.w = y1c * Ww + x1c;
  int4* op = (int4*)(prep + (size_t)idx * 4);
  op[0] = a;
  op[1] = b;
  wmask[idx] = scale;
}

// ---------------------------------------------------------------------------
// Main: wave per point. Lane L = (corner q=L>>4, channel-quad k=L&15).
// ONE dwordx4 gather per (point,s) covers all 4 corners x 64 channels (1 KB).
// Reduction: shfl_xor 16,32 (sum corners) then 1 (pair quads -> group of 8).
// Two-deep pipeline: wo two-ahead, gather one-ahead.
// ---------------------------------------------------------------------------
__global__ __launch_bounds__(256) void corr_main(
    const float* __restrict__ ref_t, const float* __restrict__ src_t,
    const WO* __restrict__ prep, float* __restrict__ corr) {
  int nwg = gridDim.x;                     // 5120, divisible by 8
  int q8 = nwg >> 3;
  int bb = blockIdx.x;
  int swz = (bb & 7) * q8 + (bb >> 3);     // bijective XCD chunking
  int wid  = threadIdx.x >> 6;
  int lane = threadIdx.x & 63;
  int k = lane & 15;                       // channel quad -> channels 4k..4k+3
  int hw = swz * 4 + wid;
  int n  = blockIdx.y;

  // ref channel quad for this point (loaded once, reused for all 16 s)
  float4 rv = *(const float4*)(ref_t + ((size_t)(n * HW) + hw) * Cc + 4 * k);
  const float* srcn = src_t + (size_t)n * HW * Cc;
  // per-corner prep stream: quarter-wave q reads its own {w,o}
  const WO* pp = prep + ((size_t)(n * Ss) * HW + hw) * 4 + (lane >> 4);
  const int PSTRIDE = HW * 4;              // WOs per s step

  // writer lanes: q==0, k even -> g = k>>1
  int cbase = ((n * Gg + (k >> 1)) * Ss) * HW + hw;

  WO wo0 = pp[0];
  float4 v0 = *(const float4*)(srcn + ((size_t)wo0.o << 6) + (k << 2));
  WO wo1 = pp[PSTRIDE];

#pragma unroll
  for (int s = 0; s < Ss; ++s) {
    WO wo2; float4 v1;
    if (s + 2 < Ss) wo2 = pp[(s + 2) * PSTRIDE];
    if (s + 1 < Ss) v1 = *(const float4*)(srcn + ((size_t)wo1.o << 6) + (k << 2));

    // partial(q,k) = w_q * dot(v4, rv4)
    float d = v0.x * rv.x;
    d = fmaf(v0.y, rv.y, d);
    d = fmaf(v0.z, rv.z, d);
    d = fmaf(v0.w, rv.w, d);
    float p = d * wo0.w;

    p += __shfl_xor(p, 16);   // sum corner bit0
    p += __shfl_xor(p, 32);   // sum corner bit1
    p += __shfl_xor(p, 1);    // pair quads -> 8-channel group

    if (lane < 16 && (lane & 1) == 0) corr[cbase + s * HW] = p;

    wo0 = wo1; wo1 = wo2; v0 = v1;
  }
}

// ---------------------------------------------------------------------------
// Legacy single-kernel fallback (no prep buffer). Plain cached stores.
// ---------------------------------------------------------------------------
template <bool NHWC>
__global__ __launch_bounds__(256) void corr_kernel(
    const float* __restrict__ ref, const float* __restrict__ src,
    const float* __restrict__ grids, const float* __restrict__ mask,
    float* __restrict__ corr, float* __restrict__ wmask) {
  int gw   = blockIdx.x * 4 + (threadIdx.x >> 6);
  int lane = threadIdx.x & 63;
  int w  = gw % Ww;
  int hn = gw / Ww;
  int h  = hn % Hh;
  int n  = hn / Hh;

  float rv = NHWC ? ref[((n * Hh + h) * Ww + w) * Cc + lane]
                  : ref[((n * Cc + lane) * Hh + h) * Ww + w];

#pragma unroll 4
  for (int s = 0; s < Ss; ++s) {
    int gbase = (((n * Ss + s) * 2) * Hh + h) * Ww + w;
    float xg = grids[gbase];
    float yg = grids[gbase + HW];
    float mk = mask[((n * Ss + s) * Hh + h) * Ww + w];

    float xn = 2.0f * xg / (float)Ww - 1.0f;
    float yn = 2.0f * yg / (float)Hh - 1.0f;
    float gx = ((xn + 1.0f) * (float)Ww - 1.0f) * 0.5f;
    float gy = ((yn + 1.0f) * (float)Hh - 1.0f) * 0.5f;

    float x0f = floorf(gx), y0f = floorf(gy);
    float dx = gx - x0f, dy = gy - y0f;
    int x0 = (int)x0f, y0 = (int)y0f;
    int x1 = x0 + 1, y1 = y0 + 1;

    float vx0 = (x0 >= 0 && x0 < Ww) ? 1.f : 0.f;
    float vx1 = (x1 >= 0 && x1 < Ww) ? 1.f : 0.f;
    float vy0 = (y0 >= 0 && y0 < Hh) ? 1.f : 0.f;
    float vy1 = (y1 >= 0 && y1 < Hh) ? 1.f : 0.f;

    float w00 = (1.f - dx) * (1.f - dy) * vx0 * vy0;
    float w10 = dx * (1.f - dy) * vx1 * vy0;
    float w01 = (1.f - dx) * dy * vx0 * vy1;
    float w11 = dx * dy * vx1 * vy1;

    float m  = w00 + w10 + w01 + w11;
    float wm = (m < 0.9999f) ? 0.f : 1.f;
    float scale = wm * mk;

    float res = 0.f;
    if (scale != 0.f) {
      int x0c = min(max(x0, 0), Ww - 1), x1c = min(max(x1, 0), Ww - 1);
      int y0c = min(max(y0, 0), Hh - 1), y1c = min(max(y1, 0), Hh - 1);
      float v00, v10, v01, v11;
      if (NHWC) {
        v00 = src[((n * Hh + y0c) * Ww + x0c) * Cc + lane];
        v10 = src[((n * Hh + y0c) * Ww + x1c) * Cc + lane];
        v01 = src[((n * Hh + y1c) * Ww + x0c) * Cc + lane];
        v11 = src[((n * Hh + y1c) * Ww + x1c) * Cc + lane];
      } else {
        const float* sp2 = src + (size_t)(n * Cc + lane) * HW;
        v00 = sp2[y0c * Ww + x0c];
        v10 = sp2[y0c * Ww + x1c];
        v01 = sp2[y1c * Ww + x0c];
        v11 = sp2[y1c * Ww + x1c];
      }
      float acc = w00 * v00 + w10 * v10 + w01 * v01 + w11 * v11;
      float p = acc * rv * scale;
      p += __shfl_xor(p, 1);
      p += __shfl_xor(p, 2);
      p += __shfl_xor(p, 4);
      res = p;
    }
    if ((lane & 7) == 0) {
      int g = lane >> 3;
      corr[((((n * Gg + g) * Ss + s) * Hh + h) * Ww) + w] = res;
    }
    if (lane == 0) wmask[((n * Ss + s) * Hh + h) * Ww + w] = scale;
  }
}

extern "C" void kernel_launch(void* const* d_in, const int* in_sizes, int n_in,
                              void* d_out, int out_size, void* d_ws, size_t ws_size,
                              hipStream_t stream) {
  const float* feat_ref = (const float*)d_in[0];
  const float* feat_src = (const float*)d_in[1];
  const float* grids    = (const float*)d_in[2];
  const float* mask     = (const float*)d_in[3];

  float* corr  = (float*)d_out;
  float* wmask = corr + (size_t)Nn * Gg * Ss * HW;

  const size_t bytes_t   = (size_t)Nn * Cc * HW * sizeof(float);  // 10.49 MB
  const size_t prep_off  = 2 * bytes_t;                           // 20.97 MB
  const size_t prep_size = (size_t)NPS * 4 * sizeof(WO);          // 20.97 MB

  if (ws_size >= prep_off + prep_size) {            // 42 MiB full path
    float* ref_t = (float*)d_ws;
    float* src_t = ref_t + (size_t)Nn * Cc * HW;
    WO*    prep  = (WO*)((char*)d_ws + prep_off);
    prep_kernel<<<dim3(HW / 256, Nn * Ss), 256, 0, stream>>>(grids, mask, prep, wmask);
    transpose2_nchw_nhwc<<<dim3(Nn * Hh * (Ww / 32), 2), 256, 0, stream>>>(
        feat_ref, feat_src, ref_t, src_t);
    corr_main<<<dim3(HW / 4, Nn), 256, 0, stream>>>(ref_t, src_t, prep, corr);
  } else if (ws_size >= 2 * bytes_t) {              // transpose-only path
    float* ref_t = (float*)d_ws;
    float* src_t = ref_t + (size_t)Nn * Cc * HW;
    transpose2_nchw_nhwc<<<dim3(Nn * Hh * (Ww / 32), 2), 256, 0, stream>>>(
        feat_ref, feat_src, ref_t, src_t);
    corr_kernel<true><<<(Nn * HW) / 4, 256, 0, stream>>>(ref_t, src_t, grids, mask, corr, wmask);
  } else {                                          // no-workspace fallback
    corr_kernel<false><<<(Nn * HW) / 4, 256, 0, stream>>>(feat_ref, feat_src, grids, mask, corr, wmask);
  }
}